// Round 8
// baseline (429.328 us; speedup 1.0000x reference)
//
#include <hip/hip_runtime.h>
#include <hip/hip_bf16.h>

typedef unsigned short u16;
typedef __attribute__((ext_vector_type(8))) short short8v;
typedef __attribute__((ext_vector_type(4))) float f32x4;

typedef __attribute__((address_space(3))) char lds_char;
typedef const __attribute__((address_space(1))) char g_char;

__device__ __forceinline__ u16 f2bf(float f) {
    union { float f; unsigned int u; } x; x.f = f;
    unsigned int u = x.u;
    return (u16)((u + 0x7FFFu + ((u >> 16) & 1u)) >> 16);
}
__device__ __forceinline__ float bf2f(u16 h) {
    union { unsigned int u; float f; } x; x.u = ((unsigned int)h) << 16;
    return x.f;
}
__device__ __forceinline__ u16 cvtbf(float f) {
    return __builtin_bit_cast(u16, __float2bfloat16(f));
}
__device__ __forceinline__ void gload16(const void* g, void* l) {
    __builtin_amdgcn_global_load_lds((g_char*)g, (lds_char*)l, 16, 0, 0);
}

// ---------------------------------------------------------------------------
// m97-style 128x128 bf16 MFMA GEMM, BK=64. 256 thr = 4 waves (2x2), wave tile
// 64x64 (4x4 frags of 16x16x32). SINGLE-buffer LDS: A 16KB bf16 + B 16KB bf16
// = 32KB. Plain 2-barrier loop; latency hiding via 3 blocks/CU co-residency
// (m97/m114). LDS is ALWAYS bf16:
//   - bf16 A: DMA via global_load_lds, pre-swizzled source.
//   - fp32 A (AF32): reg-staged  global->VGPR(8xfloat4)->cvt->swizzled
//     ds_write_b128. Keeps Ges single-read from HBM, halves A LDS bytes vs
//     fp32-in-LDS (r7's pole: 144KB -> 96KB per block-K-step), and removes
//     all cvts from the fragment path.
// Split-K: blockIdx.z handles K-chunk [z*K,(z+1)*K); EPI=4 stores f32 partial.
// EPI: 0 = store bf16, 4 = store f32 partial at P + z*8192*ldc.
// ---------------------------------------------------------------------------
template<int EPI, bool AF32>
__global__ __launch_bounds__(256, 3) void gemm_k(
    const void* __restrict__ Ap, int lda,
    const u16* __restrict__ Bt, int ldb,
    void* __restrict__ Cp, int ldc, int K)
{
    __shared__ alignas(16) char smem[32768];   // A 16K | B 16K

    const int t     = threadIdx.x;
    const int lane  = t & 63;
    const int wid   = t >> 6;
    const int m0    = blockIdx.x * 128;
    const int n0    = blockIdx.y * 128;
    const int kbase = blockIdx.z * K;
    const int wr    = wid >> 1, wc = wid & 1;
    const int lr    = lane & 15, q4 = lane >> 4;

    f32x4 acc[4][4];
    #pragma unroll
    for (int i = 0; i < 4; ++i)
        #pragma unroll
        for (int j = 0; j < 4; ++j)
            acc[i][j] = (f32x4){0.f, 0.f, 0.f, 0.f};

    const int nsteps = K >> 6;
    for (int kt = 0; kt < nsteps; ++kt) {
        const int k0 = kbase + (kt << 6);

        float4 ar[8];
        if constexpr (AF32) {
            // ---- A: issue 8 float4 global loads FIRST (B DMA stays behind) ----
            const float* A32 = (const float*)Ap;
            #pragma unroll
            for (int p = 0; p < 4; ++p) {
                int o   = p * 4096 + t * 16;        // bf16-tile byte offset
                int row = o >> 7;
                int fc  = (o & 127) >> 1;           // fp32 col (8 floats/chunk)
                const float* gp = A32 + (size_t)(m0 + row) * (size_t)lda + k0 + fc;
                ar[2 * p]     = *(const float4*)gp;
                ar[2 * p + 1] = *(const float4*)(gp + 4);
            }
        } else {
            // ---- A: DMA, pre-swizzled source -> linear LDS ----
            const u16* A16 = (const u16*)Ap;
            #pragma unroll
            for (int p = 0; p < 4; ++p) {
                int o   = p * 4096 + t * 16;
                int row = o >> 7;
                int cb  = (o & 127) ^ ((row & 7) << 4);
                gload16(A16 + (size_t)(m0 + row) * (size_t)lda + k0 + (cb >> 1),
                        smem + o);
            }
        }
        // ---- B: DMA ----
        #pragma unroll
        for (int p = 0; p < 4; ++p) {
            int o   = p * 4096 + t * 16;
            int row = o >> 7;
            int cb  = (o & 127) ^ ((row & 7) << 4);
            gload16(Bt + (size_t)(n0 + row) * (size_t)ldb + k0 + (cb >> 1),
                    smem + 16384 + o);
        }
        if constexpr (AF32) {
            // ---- cvt + swizzled ds_write (compiler waits on ar only) ----
            #pragma unroll
            for (int p = 0; p < 4; ++p) {
                int o   = p * 4096 + t * 16;
                int row = o >> 7;
                int cb  = o & 127;
                const float* f0 = (const float*)&ar[2 * p];
                const float* f1 = (const float*)&ar[2 * p + 1];
                uint4 w;
                w.x = (unsigned)cvtbf(f0[0]) | ((unsigned)cvtbf(f0[1]) << 16);
                w.y = (unsigned)cvtbf(f0[2]) | ((unsigned)cvtbf(f0[3]) << 16);
                w.z = (unsigned)cvtbf(f1[0]) | ((unsigned)cvtbf(f1[1]) << 16);
                w.w = (unsigned)cvtbf(f1[2]) | ((unsigned)cvtbf(f1[3]) << 16);
                *(uint4*)(smem + row * 128 + (cb ^ ((row & 7) << 4))) = w;
            }
        }
        __syncthreads();   // vmcnt(0)+lgkmcnt(0) drain + barrier: tile visible

        // ---- compute (LDS is bf16 for both operands, always) ----
        #pragma unroll
        for (int kh = 0; kh < 2; ++kh) {
            short8v a[4], b[4];
            #pragma unroll
            for (int i = 0; i < 4; ++i) {
                int arr = wr * 64 + i * 16 + lr;
                a[i] = *(const short8v*)(smem + arr * 128 +
                        ((kh * 64 + q4 * 16) ^ ((arr & 7) << 4)));
            }
            #pragma unroll
            for (int i = 0; i < 4; ++i) {
                int br = wc * 64 + i * 16 + lr;
                b[i] = *(const short8v*)(smem + 16384 + br * 128 +
                        ((kh * 64 + q4 * 16) ^ ((br & 7) << 4)));
            }
            #pragma unroll
            for (int mi = 0; mi < 4; ++mi)
                #pragma unroll
                for (int ni = 0; ni < 4; ++ni)
                    acc[mi][ni] = __builtin_amdgcn_mfma_f32_16x16x32_bf16(
                        a[mi], b[ni], acc[mi][ni], 0, 0, 0);
        }
        __syncthreads();   // all reads done before next stage overwrites
    }

    // ---- epilogue ----
    const size_t zoff = (size_t)blockIdx.z * 8192ull * (size_t)ldc;
    #pragma unroll
    for (int mi = 0; mi < 4; ++mi) {
        #pragma unroll
        for (int ni = 0; ni < 4; ++ni) {
            const int gc = n0 + wc * 64 + ni * 16 + lr;
            #pragma unroll
            for (int j = 0; j < 4; ++j) {
                const int gr = m0 + wr * 64 + mi * 16 + q4 * 4 + j;
                float v = acc[mi][ni][j];
                if constexpr (EPI == 0) {
                    ((u16*)Cp)[(size_t)gr * ldc + gc] = f2bf(v);
                } else {
                    ((float*)Cp)[zoff + (size_t)gr * ldc + gc] = v;
                }
            }
        }
    }
}

// ---------------------------------------------------------------------------
// Split-K combine + fused epilogues over [8192 x 512].
// MODE 1: AH[r][c]      = bf16( (sum_z P) * V[r][c] )        (guided * V)
// MODE 2: AH[r][512+c]  = bf16( gelu( sum_z P + b1[c] ) )    (MLP hidden)
// MODE 3: out[r][c]     = sum_z P + bsum[c]                   (final, f32)
// ---------------------------------------------------------------------------
template<int KZ, int MODE>
__global__ void k_cmb(const float* __restrict__ P, const u16* __restrict__ QKV,
                      const float* __restrict__ bvec, void* __restrict__ dst)
{
    for (int i = blockIdx.x * 256 + threadIdx.x; i < 1048576;
         i += gridDim.x * 256) {
        const int r = i >> 7, c = (i & 127) * 4;
        f32x4 s = ((const f32x4*)P)[i];
        #pragma unroll
        for (int z = 1; z < KZ; ++z) {
            f32x4 q = ((const f32x4*)P)[(size_t)z * 1048576 + i];
            s[0] += q[0]; s[1] += q[1]; s[2] += q[2]; s[3] += q[3];
        }
        if constexpr (MODE == 1) {
            ushort4 v = *(const ushort4*)(QKV + (size_t)r * 1536 + 1024 + c);
            ushort4 o;
            o.x = cvtbf(s[0] * bf2f(v.x)); o.y = cvtbf(s[1] * bf2f(v.y));
            o.z = cvtbf(s[2] * bf2f(v.z)); o.w = cvtbf(s[3] * bf2f(v.w));
            *(ushort4*)((u16*)dst + (size_t)r * 1024 + c) = o;
        } else if constexpr (MODE == 2) {
            float4 b = *(const float4*)(bvec + c);
            float x0 = s[0] + b.x, x1 = s[1] + b.y, x2 = s[2] + b.z, x3 = s[3] + b.w;
            ushort4 o;
            o.x = cvtbf(0.5f * x0 * (1.0f + erff(x0 * 0.70710678118f)));
            o.y = cvtbf(0.5f * x1 * (1.0f + erff(x1 * 0.70710678118f)));
            o.z = cvtbf(0.5f * x2 * (1.0f + erff(x2 * 0.70710678118f)));
            o.w = cvtbf(0.5f * x3 * (1.0f + erff(x3 * 0.70710678118f)));
            *(ushort4*)((u16*)dst + (size_t)r * 1024 + 512 + c) = o;
        } else {
            float4 b = *(const float4*)(bvec + c);
            float4 o = {s[0] + b.x, s[1] + b.y, s[2] + b.z, s[3] + b.w};
            *(float4*)((float*)dst + (size_t)r * 512 + c) = o;
        }
    }
}

// ---------------------------------------------------------------------------
// Convert Wq|Wk|Wv (concat) and W1 to bf16 (x_in/Ges consumed fp32 directly).
// ---------------------------------------------------------------------------
__global__ void k_convert(const float* __restrict__ Wq, const float* __restrict__ Wk,
                          const float* __restrict__ Wv, const float* __restrict__ W1,
                          u16* __restrict__ WqkvB, u16* __restrict__ W1B)
{
    const int C2 = 196608;   // Wqkv float4 chunks
    const int C3 = 65536;    // W1 chunks
    for (int i = blockIdx.x * blockDim.x + threadIdx.x; i < C2 + C3;
         i += gridDim.x * blockDim.x) {
        const float* src; u16* dst;
        if (i < C2) {
            int e = i * 4;
            if (e < 262144)      src = Wq + e;
            else if (e < 524288) src = Wk + (e - 262144);
            else                 src = Wv + (e - 524288);
            dst = WqkvB + e;
        } else {
            int e = (i - C2) * 4;
            src = W1 + e; dst = W1B + e;
        }
        float4 v = *reinterpret_cast<const float4*>(src);
        ushort4 h;
        h.x = f2bf(v.x); h.y = f2bf(v.y); h.z = f2bf(v.z); h.w = f2bf(v.w);
        *reinterpret_cast<ushort4*>(dst) = h;
    }
}

// ---------------------------------------------------------------------------
// TXT[c][m] = bf16(task_x[m][c])  — 64x64 tiles through LDS.
// ---------------------------------------------------------------------------
__global__ void k_transpose(const float* __restrict__ tx, u16* __restrict__ txt)
{
    __shared__ float tile[64][65];
    const int n0 = blockIdx.x * 64;
    const int c0 = blockIdx.y * 64;
    const int t = threadIdx.x;
    #pragma unroll
    for (int p = 0; p < 4; ++p) {
        int q = p * 256 + t;
        int r = q >> 4, s = q & 15;
        float4 v = *reinterpret_cast<const float4*>(tx + (size_t)(n0 + r) * 512 + c0 + s * 4);
        tile[r][s * 4 + 0] = v.x; tile[r][s * 4 + 1] = v.y;
        tile[r][s * 4 + 2] = v.z; tile[r][s * 4 + 3] = v.w;
    }
    __syncthreads();
    #pragma unroll
    for (int p = 0; p < 4; ++p) {
        int q = p * 256 + t;
        int cc = q >> 4, s = q & 15;
        ushort4 h;
        h.x = f2bf(tile[s * 4 + 0][cc]); h.y = f2bf(tile[s * 4 + 1][cc]);
        h.z = f2bf(tile[s * 4 + 2][cc]); h.w = f2bf(tile[s * 4 + 3][cc]);
        *reinterpret_cast<ushort4*>(txt + (size_t)(c0 + cc) * 8192 + n0 + s * 4) = h;
    }
}

// ---------------------------------------------------------------------------
// colsq[j] = sum_n QKV[n,j]^2, j in [0,1024)
// ---------------------------------------------------------------------------
__global__ void k_colsq(const u16* __restrict__ QKV, float* __restrict__ colsq)
{
    const int t = threadIdx.x;
    const int c8 = t & 127, rs = t >> 7;
    float a[8];
    #pragma unroll
    for (int j = 0; j < 8; ++j) a[j] = 0.f;
    const int row0 = blockIdx.x * 64;
    for (int rr = rs; rr < 64; rr += 2) {
        uint4 u = *reinterpret_cast<const uint4*>(QKV + (size_t)(row0 + rr) * 1536 + c8 * 8);
        unsigned int w[4] = {u.x, u.y, u.z, u.w};
        #pragma unroll
        for (int q = 0; q < 4; ++q) {
            float f0 = bf2f((u16)(w[q] & 0xffffu));
            float f1 = bf2f((u16)(w[q] >> 16));
            a[2 * q]     += f0 * f0;
            a[2 * q + 1] += f1 * f1;
        }
    }
    #pragma unroll
    for (int j = 0; j < 8; ++j) atomicAdd(&colsq[c8 * 8 + j], a[j]);
}

// ---------------------------------------------------------------------------
// Per-head Gram partials: S[h,d,e] += sum_{n in chunk} K[n,h64+d]*Q[n,h64+e]
// 16-row LDS tiles: 16 barriers/block (was 64), all 256 threads load.
// ---------------------------------------------------------------------------
__global__ void k_gram(const u16* __restrict__ QKV, float* __restrict__ Sb)
{
    __shared__ u16 Qt[16][64];
    __shared__ u16 Kt[16][64];
    const int h = blockIdx.x >> 6;
    const int chunk = blockIdx.x & 63;
    const int t = threadIdx.x;
    const int e = t & 63;
    const int dg = t >> 6;
    float acc[16];
    #pragma unroll
    for (int k = 0; k < 16; ++k) acc[k] = 0.f;
    const int rowbase = chunk * 128;
    for (int p = 0; p < 8; ++p) {
        __syncthreads();
        {
            const int mat = t >> 7, sub = t & 127, r = sub >> 3, seg = sub & 7;
            const int row = rowbase + p * 16 + r;
            const int col = (mat ? 512 : 0) + h * 64 + seg * 8;
            uint4 v = *reinterpret_cast<const uint4*>(QKV + (size_t)row * 1536 + col);
            u16* dst = mat ? &Kt[r][seg * 8] : &Qt[r][seg * 8];
            *reinterpret_cast<uint4*>(dst) = v;
        }
        __syncthreads();
        #pragma unroll
        for (int r = 0; r < 16; ++r) {
            const float q = bf2f(Qt[r][e]);
            short8v kv0 = *reinterpret_cast<const short8v*>(&Kt[r][dg * 16]);
            short8v kv1 = *reinterpret_cast<const short8v*>(&Kt[r][dg * 16 + 8]);
            #pragma unroll
            for (int k = 0; k < 8; ++k) {
                acc[k]     += bf2f((u16)kv0[k]) * q;
                acc[k + 8] += bf2f((u16)kv1[k]) * q;
            }
        }
    }
    #pragma unroll
    for (int k = 0; k < 16; ++k)
        atomicAdd(&Sb[h * 4096 + (dg * 16 + k) * 64 + e], acc[k]);
}

// ---------------------------------------------------------------------------
// attn[h,d,e] = softmax_e( S/(||k_d|| ||q_e||) * rescale[h] )
// ---------------------------------------------------------------------------
__global__ void k_softmax(const float* __restrict__ Sb, const float* __restrict__ colsq,
                          const float* __restrict__ rescale, float* __restrict__ Abuf)
{
    const int h = blockIdx.x;
    const int t = threadIdx.x;   // 64
    const float rsc = rescale[h];
    const float nq = fmaxf(sqrtf(colsq[h * 64 + t]), 1e-12f);
    for (int d = 0; d < 64; ++d) {
        const float nk = fmaxf(sqrtf(colsq[512 + h * 64 + d]), 1e-12f);
        float v = Sb[h * 4096 + d * 64 + t] / (nk * nq) * rsc;
        float m = v;
        #pragma unroll
        for (int off = 32; off > 0; off >>= 1) m = fmaxf(m, __shfl_xor(m, off, 64));
        float p = expf(v - m);
        float s = p;
        #pragma unroll
        for (int off = 32; off > 0; off >>= 1) s += __shfl_xor(s, off, 64);
        Abuf[h * 4096 + d * 64 + t] = p / s;
    }
}

// ---------------------------------------------------------------------------
// BtC[j][c]: c<512 -> fold attn with Wp; c>=512 -> W2. bsum[j] = bp[j]+b2[j].
// ---------------------------------------------------------------------------
__global__ void k_buildbt(const float* __restrict__ Abuf, const float* __restrict__ Wp,
                          const float* __restrict__ W2, const float* __restrict__ bp,
                          const float* __restrict__ b2, u16* __restrict__ BtC,
                          float* __restrict__ bsum)
{
    const int g = blockIdx.x * 256 + threadIdx.x;
    const int j = g >> 10, c = g & 1023;
    if (c < 512) {
        const int h = c >> 6, e = c & 63;
        const float* Ah = Abuf + h * 4096 + e;
        const float* Wph = Wp + (size_t)j * 512 + h * 64;
        float s = 0.f;
        #pragma unroll 8
        for (int d = 0; d < 64; ++d) s += Ah[d * 64] * Wph[d];
        BtC[(size_t)j * 1024 + c] = f2bf(s);
        if (c == 0) bsum[j] = bp[j] + b2[j];
    } else {
        BtC[(size_t)j * 1024 + c] = f2bf(W2[(size_t)j * 512 + (c - 512)]);
    }
}

// ---------------------------------------------------------------------------
extern "C" void kernel_launch(void* const* d_in, const int* in_sizes, int n_in,
                              void* d_out, int out_size, void* d_ws, size_t ws_size,
                              hipStream_t stream)
{
    const float* x_in    = (const float*)d_in[0];
    const float* task_x  = (const float*)d_in[1];
    const float* Ges     = (const float*)d_in[2];
    const float* Wq      = (const float*)d_in[3];
    const float* Wk      = (const float*)d_in[4];
    const float* Wv      = (const float*)d_in[5];
    const float* rescale = (const float*)d_in[6];
    const float* Wp      = (const float*)d_in[7];
    const float* bp      = (const float*)d_in[8];
    const float* W1      = (const float*)d_in[9];
    const float* b1      = (const float*)d_in[10];
    const float* W2      = (const float*)d_in[11];
    const float* b2      = (const float*)d_in[12];
    float* out = (float*)d_out;
    char* ws = (char*)d_ws;

    u16*   TXT   = (u16*)  (ws + 0);            //  512x8192  bf16 (8 MB)
    u16*   QKV   = (u16*)  (ws + 8388608);      //  8192x1536 bf16 (25 MB)
    u16*   AH    = (u16*)  (ws + 33554432);     //  8192x1024 bf16 (17 MB)
    u16*   WqkvB = (u16*)  (ws + 50331648);     //  1536x512  bf16
    u16*   W1B   = (u16*)  (ws + 51904512);     //  512x512   bf16
    u16*   BtC   = (u16*)  (ws + 52428800);     //  512x1024  bf16
    float* colsq = (float*)(ws + 53477376);     //  1024 f32
    float* Sb    = (float*)(ws + 53481472);     //  8x64x64 f32
    float* Abuf  = (float*)(ws + 53612544);     //  8x64x64 f32
    float* bsum  = (float*)(ws + 53743616);     //  512 f32
    float* P     = (float*)(ws + 53745664);     //  up to 4 x 8192x512 f32 (64 MB)
    (void)in_sizes; (void)n_in; (void)out_size; (void)ws_size;

    hipMemsetAsync(colsq, 0, 135168, stream);   // colsq + Sb

    k_convert  <<<512, 256, 0, stream>>>(Wq, Wk, Wv, W1, WqkvB, W1B);
    k_transpose<<<dim3(128, 8), 256, 0, stream>>>(task_x, TXT);

    // QKV = x @ [Wq;Wk;Wv]^T  (M=8192, N=1536, K=512; A = x_in fp32; 768 blk)
    gemm_k<0, true><<<dim3(64, 12, 1), 256, 0, stream>>>(
        x_in, 512, WqkvB, 512, QKV, 1536, 512);

    k_colsq  <<<128, 256, 0, stream>>>(QKV, colsq);
    k_gram   <<<512, 256, 0, stream>>>(QKV, Sb);
    k_softmax<<<8, 64, 0, stream>>>(Sb, colsq, rescale, Abuf);
    k_buildbt<<<2048, 256, 0, stream>>>(Abuf, Wp, W2, bp, b2, BtC, bsum);

    // guided partials: Ges @ TXT^T  (M=8192, N=512, K=8192, split-K=4 -> 1024 blk)
    gemm_k<4, true><<<dim3(64, 4, 4), 256, 0, stream>>>(
        Ges, 8192, TXT, 8192, P, 512, 2048);
    k_cmb<4, 1><<<1024, 256, 0, stream>>>(P, QKV, nullptr, AH);

    // hidden partials: V @ W1^T  (K=512, split-K=2 -> 512 blk)
    gemm_k<4, false><<<dim3(64, 4, 2), 256, 0, stream>>>(
        QKV + 1024, 1536, W1B, 512, P, 512, 256);
    k_cmb<2, 2><<<1024, 256, 0, stream>>>(P, nullptr, b1, AH);

    // final partials: [guided|hidden] @ BtC^T  (K=1024, split-K=2 -> 512 blk)
    gemm_k<4, false><<<dim3(64, 4, 2), 256, 0, stream>>>(
        AH, 1024, BtC, 1024, P, 512, 512);
    k_cmb<2, 3><<<1024, 256, 0, stream>>>(P, nullptr, bsum, out);
}

// Round 9
// 417.119 us; speedup vs baseline: 1.0293x; 1.0293x over previous
//
#include <hip/hip_runtime.h>
#include <hip/hip_bf16.h>

typedef unsigned short u16;
typedef __attribute__((ext_vector_type(8))) short short8v;
typedef __attribute__((ext_vector_type(4))) float f32x4;

typedef __attribute__((address_space(3))) char lds_char;
typedef const __attribute__((address_space(1))) char g_char;

__device__ __forceinline__ u16 f2bf(float f) {
    union { float f; unsigned int u; } x; x.f = f;
    unsigned int u = x.u;
    return (u16)((u + 0x7FFFu + ((u >> 16) & 1u)) >> 16);
}
__device__ __forceinline__ float bf2f(u16 h) {
    union { unsigned int u; float f; } x; x.u = ((unsigned int)h) << 16;
    return x.f;
}
__device__ __forceinline__ u16 cvtbf(float f) {
    return __builtin_bit_cast(u16, __float2bfloat16(f));
}
__device__ __forceinline__ void gload16(const void* g, void* l) {
    __builtin_amdgcn_global_load_lds((g_char*)g, (lds_char*)l, 16, 0, 0);
}

// ---------------------------------------------------------------------------
// m97-style 128x128 bf16 MFMA GEMM, BK=64. 256 thr = 4 waves (2x2), wave tile
// 64x64 (4x4 frags of 16x16x32). Single-buffer LDS 32KB (A 16K | B 16K),
// ALL operands bf16, ALL staging via global_load_lds (pre-swizzled source,
// nothing on the issue->barrier path). Plain 2-barrier loop; latency hiding
// via 4-5 co-resident blocks/CU (m97/m114 mechanism).
// Split-K: blockIdx.z handles K-chunk [z*K,(z+1)*K).
// EPI: 0 = store bf16, 4 = store f32 partial at P + z*8192*ldc.
// ---------------------------------------------------------------------------
template<int EPI>
__global__ __launch_bounds__(256, 4) void gemm_k(
    const u16* __restrict__ Ab, int lda,
    const u16* __restrict__ Bt, int ldb,
    void* __restrict__ Cp, int ldc, int K)
{
    __shared__ alignas(16) char smem[32768];   // A 16K | B 16K

    const int t     = threadIdx.x;
    const int lane  = t & 63;
    const int wid   = t >> 6;
    const int m0    = blockIdx.x * 128;
    const int n0    = blockIdx.y * 128;
    const int kbase = blockIdx.z * K;
    const int wr    = wid >> 1, wc = wid & 1;
    const int lr    = lane & 15, q4 = lane >> 4;

    f32x4 acc[4][4];
    #pragma unroll
    for (int i = 0; i < 4; ++i)
        #pragma unroll
        for (int j = 0; j < 4; ++j)
            acc[i][j] = (f32x4){0.f, 0.f, 0.f, 0.f};

    const int nsteps = K >> 6;
    for (int kt = 0; kt < nsteps; ++kt) {
        const int k0 = kbase + (kt << 6);
        // ---- stage A + B (DMA only; pre-swizzled source -> linear LDS) ----
        #pragma unroll
        for (int p = 0; p < 4; ++p) {
            int o   = p * 4096 + t * 16;
            int row = o >> 7;
            int cb  = (o & 127) ^ ((row & 7) << 4);
            gload16(Ab + (size_t)(m0 + row) * (size_t)lda + k0 + (cb >> 1),
                    smem + o);
        }
        #pragma unroll
        for (int p = 0; p < 4; ++p) {
            int o   = p * 4096 + t * 16;
            int row = o >> 7;
            int cb  = (o & 127) ^ ((row & 7) << 4);
            gload16(Bt + (size_t)(n0 + row) * (size_t)ldb + k0 + (cb >> 1),
                    smem + 16384 + o);
        }
        __syncthreads();   // vmcnt(0) drain + barrier: tile visible to all waves

        // ---- compute ----
        #pragma unroll
        for (int kh = 0; kh < 2; ++kh) {
            short8v a[4], b[4];
            #pragma unroll
            for (int i = 0; i < 4; ++i) {
                int ar = wr * 64 + i * 16 + lr;
                a[i] = *(const short8v*)(smem + ar * 128 +
                        ((kh * 64 + q4 * 16) ^ ((ar & 7) << 4)));
            }
            #pragma unroll
            for (int i = 0; i < 4; ++i) {
                int br = wc * 64 + i * 16 + lr;
                b[i] = *(const short8v*)(smem + 16384 + br * 128 +
                        ((kh * 64 + q4 * 16) ^ ((br & 7) << 4)));
            }
            #pragma unroll
            for (int mi = 0; mi < 4; ++mi)
                #pragma unroll
                for (int ni = 0; ni < 4; ++ni)
                    acc[mi][ni] = __builtin_amdgcn_mfma_f32_16x16x32_bf16(
                        a[mi], b[ni], acc[mi][ni], 0, 0, 0);
        }
        __syncthreads();   // all reads done before next stage overwrites
    }

    // ---- epilogue ----
    const size_t zoff = (size_t)blockIdx.z * 8192ull * (size_t)ldc;
    #pragma unroll
    for (int mi = 0; mi < 4; ++mi) {
        #pragma unroll
        for (int ni = 0; ni < 4; ++ni) {
            const int gc = n0 + wc * 64 + ni * 16 + lr;
            #pragma unroll
            for (int j = 0; j < 4; ++j) {
                const int gr = m0 + wr * 64 + mi * 16 + q4 * 4 + j;
                float v = acc[mi][ni][j];
                if constexpr (EPI == 0) {
                    ((u16*)Cp)[(size_t)gr * ldc + gc] = f2bf(v);
                } else {
                    ((float*)Cp)[zoff + (size_t)gr * ldc + gc] = v;
                }
            }
        }
    }
}

// ---------------------------------------------------------------------------
// Split-K combine + fused epilogues over [8192 x 512].
// MODE 1: AH[r][c]      = bf16( (sum_z P) * V[r][c] )        (guided * V)
// MODE 2: AH[r][512+c]  = bf16( gelu( sum_z P + b1[c] ) )    (MLP hidden)
// MODE 3: out[r][c]     = sum_z P + bsum[c]                   (final, f32)
// ---------------------------------------------------------------------------
template<int KZ, int MODE>
__global__ void k_cmb(const float* __restrict__ P, const u16* __restrict__ QKV,
                      const float* __restrict__ bvec, void* __restrict__ dst)
{
    for (int i = blockIdx.x * 256 + threadIdx.x; i < 1048576;
         i += gridDim.x * 256) {
        const int r = i >> 7, c = (i & 127) * 4;
        f32x4 s = ((const f32x4*)P)[i];
        #pragma unroll
        for (int z = 1; z < KZ; ++z) {
            f32x4 q = ((const f32x4*)P)[(size_t)z * 1048576 + i];
            s[0] += q[0]; s[1] += q[1]; s[2] += q[2]; s[3] += q[3];
        }
        if constexpr (MODE == 1) {
            ushort4 v = *(const ushort4*)(QKV + (size_t)r * 1536 + 1024 + c);
            ushort4 o;
            o.x = cvtbf(s[0] * bf2f(v.x)); o.y = cvtbf(s[1] * bf2f(v.y));
            o.z = cvtbf(s[2] * bf2f(v.z)); o.w = cvtbf(s[3] * bf2f(v.w));
            *(ushort4*)((u16*)dst + (size_t)r * 1024 + c) = o;
        } else if constexpr (MODE == 2) {
            float4 b = *(const float4*)(bvec + c);
            float x0 = s[0] + b.x, x1 = s[1] + b.y, x2 = s[2] + b.z, x3 = s[3] + b.w;
            ushort4 o;
            o.x = cvtbf(0.5f * x0 * (1.0f + erff(x0 * 0.70710678118f)));
            o.y = cvtbf(0.5f * x1 * (1.0f + erff(x1 * 0.70710678118f)));
            o.z = cvtbf(0.5f * x2 * (1.0f + erff(x2 * 0.70710678118f)));
            o.w = cvtbf(0.5f * x3 * (1.0f + erff(x3 * 0.70710678118f)));
            *(ushort4*)((u16*)dst + (size_t)r * 1024 + 512 + c) = o;
        } else {
            float4 b = *(const float4*)(bvec + c);
            float4 o = {s[0] + b.x, s[1] + b.y, s[2] + b.z, s[3] + b.w};
            *(float4*)((float*)dst + (size_t)r * 512 + c) = o;
        }
    }
}

// ---------------------------------------------------------------------------
// Ges fp32 -> bf16, streaming (8 floats / thread-iter, 16B stores).
// ---------------------------------------------------------------------------
__global__ void k_cges(const float* __restrict__ g, u16* __restrict__ gb)
{
    const int total = 8388608;   // chunks of 8 floats (8192*8192/8)
    for (int i = blockIdx.x * 256 + threadIdx.x; i < total;
         i += gridDim.x * 256) {
        const float4* s = (const float4*)(g + (size_t)i * 8);
        float4 a = s[0], b = s[1];
        uint4 o;
        o.x = (unsigned)cvtbf(a.x) | ((unsigned)cvtbf(a.y) << 16);
        o.y = (unsigned)cvtbf(a.z) | ((unsigned)cvtbf(a.w) << 16);
        o.z = (unsigned)cvtbf(b.x) | ((unsigned)cvtbf(b.y) << 16);
        o.w = (unsigned)cvtbf(b.z) | ((unsigned)cvtbf(b.w) << 16);
        *(uint4*)(gb + (size_t)i * 8) = o;
    }
}

// ---------------------------------------------------------------------------
// Convert x_in, Wq|Wk|Wv (concat), W1 to bf16.
// ---------------------------------------------------------------------------
__global__ void k_convert(const float* __restrict__ x_in,
                          const float* __restrict__ Wq, const float* __restrict__ Wk,
                          const float* __restrict__ Wv, const float* __restrict__ W1,
                          u16* __restrict__ XB, u16* __restrict__ WqkvB,
                          u16* __restrict__ W1B)
{
    const int C1 = 1048576;   // x_in float4 chunks
    const int C2 = 196608;    // Wqkv
    const int C3 = 65536;     // W1
    for (int i = blockIdx.x * blockDim.x + threadIdx.x; i < C1 + C2 + C3;
         i += gridDim.x * blockDim.x) {
        const float* src; u16* dst;
        if (i < C1) { src = x_in + (size_t)i * 4; dst = XB + (size_t)i * 4; }
        else if (i < C1 + C2) {
            int e = (i - C1) * 4;
            if (e < 262144)      src = Wq + e;
            else if (e < 524288) src = Wk + (e - 262144);
            else                 src = Wv + (e - 524288);
            dst = WqkvB + e;
        } else {
            int e = (i - C1 - C2) * 4;
            src = W1 + e; dst = W1B + e;
        }
        float4 v = *reinterpret_cast<const float4*>(src);
        ushort4 h;
        h.x = f2bf(v.x); h.y = f2bf(v.y); h.z = f2bf(v.z); h.w = f2bf(v.w);
        *reinterpret_cast<ushort4*>(dst) = h;
    }
}

// ---------------------------------------------------------------------------
// TXT[c][m] = bf16(task_x[m][c])  — 64x64 tiles through LDS.
// ---------------------------------------------------------------------------
__global__ void k_transpose(const float* __restrict__ tx, u16* __restrict__ txt)
{
    __shared__ float tile[64][65];
    const int n0 = blockIdx.x * 64;
    const int c0 = blockIdx.y * 64;
    const int t = threadIdx.x;
    #pragma unroll
    for (int p = 0; p < 4; ++p) {
        int q = p * 256 + t;
        int r = q >> 4, s = q & 15;
        float4 v = *reinterpret_cast<const float4*>(tx + (size_t)(n0 + r) * 512 + c0 + s * 4);
        tile[r][s * 4 + 0] = v.x; tile[r][s * 4 + 1] = v.y;
        tile[r][s * 4 + 2] = v.z; tile[r][s * 4 + 3] = v.w;
    }
    __syncthreads();
    #pragma unroll
    for (int p = 0; p < 4; ++p) {
        int q = p * 256 + t;
        int cc = q >> 4, s = q & 15;
        ushort4 h;
        h.x = f2bf(tile[s * 4 + 0][cc]); h.y = f2bf(tile[s * 4 + 1][cc]);
        h.z = f2bf(tile[s * 4 + 2][cc]); h.w = f2bf(tile[s * 4 + 3][cc]);
        *reinterpret_cast<ushort4*>(txt + (size_t)(c0 + cc) * 8192 + n0 + s * 4) = h;
    }
}

// ---------------------------------------------------------------------------
// colsq[j] = sum_n QKV[n,j]^2, j in [0,1024)
// ---------------------------------------------------------------------------
__global__ void k_colsq(const u16* __restrict__ QKV, float* __restrict__ colsq)
{
    const int t = threadIdx.x;
    const int c8 = t & 127, rs = t >> 7;
    float a[8];
    #pragma unroll
    for (int j = 0; j < 8; ++j) a[j] = 0.f;
    const int row0 = blockIdx.x * 64;
    for (int rr = rs; rr < 64; rr += 2) {
        uint4 u = *reinterpret_cast<const uint4*>(QKV + (size_t)(row0 + rr) * 1536 + c8 * 8);
        unsigned int w[4] = {u.x, u.y, u.z, u.w};
        #pragma unroll
        for (int q = 0; q < 4; ++q) {
            float f0 = bf2f((u16)(w[q] & 0xffffu));
            float f1 = bf2f((u16)(w[q] >> 16));
            a[2 * q]     += f0 * f0;
            a[2 * q + 1] += f1 * f1;
        }
    }
    #pragma unroll
    for (int j = 0; j < 8; ++j) atomicAdd(&colsq[c8 * 8 + j], a[j]);
}

// ---------------------------------------------------------------------------
// Per-head Gram partials: S[h,d,e] += sum_{n in chunk} K[n,h64+d]*Q[n,h64+e]
// ---------------------------------------------------------------------------
__global__ void k_gram(const u16* __restrict__ QKV, float* __restrict__ Sb)
{
    __shared__ u16 Qt[4][64];
    __shared__ u16 Kt[4][64];
    const int h = blockIdx.x >> 6;
    const int chunk = blockIdx.x & 63;
    const int t = threadIdx.x;
    const int e = t & 63;
    const int dg = t >> 6;
    float acc[16];
    #pragma unroll
    for (int k = 0; k < 16; ++k) acc[k] = 0.f;
    const int rowbase = chunk * 128;
    for (int p = 0; p < 32; ++p) {
        __syncthreads();
        if (t < 64) {
            const int mat = t >> 5, sub = t & 31, r = sub >> 3, seg = sub & 7;
            const int row = rowbase + p * 4 + r;
            const int col = (mat ? 512 : 0) + h * 64 + seg * 8;
            uint4 v = *reinterpret_cast<const uint4*>(QKV + (size_t)row * 1536 + col);
            u16* dst = mat ? &Kt[r][seg * 8] : &Qt[r][seg * 8];
            *reinterpret_cast<uint4*>(dst) = v;
        }
        __syncthreads();
        #pragma unroll
        for (int r = 0; r < 4; ++r) {
            const float q = bf2f(Qt[r][e]);
            short8v kv0 = *reinterpret_cast<const short8v*>(&Kt[r][dg * 16]);
            short8v kv1 = *reinterpret_cast<const short8v*>(&Kt[r][dg * 16 + 8]);
            #pragma unroll
            for (int k = 0; k < 8; ++k) {
                acc[k]     += bf2f((u16)kv0[k]) * q;
                acc[k + 8] += bf2f((u16)kv1[k]) * q;
            }
        }
    }
    #pragma unroll
    for (int k = 0; k < 16; ++k)
        atomicAdd(&Sb[h * 4096 + (dg * 16 + k) * 64 + e], acc[k]);
}

// ---------------------------------------------------------------------------
// attn[h,d,e] = softmax_e( S/(||k_d|| ||q_e||) * rescale[h] )
// ---------------------------------------------------------------------------
__global__ void k_softmax(const float* __restrict__ Sb, const float* __restrict__ colsq,
                          const float* __restrict__ rescale, float* __restrict__ Abuf)
{
    const int h = blockIdx.x;
    const int t = threadIdx.x;   // 64
    const float rsc = rescale[h];
    const float nq = fmaxf(sqrtf(colsq[h * 64 + t]), 1e-12f);
    for (int d = 0; d < 64; ++d) {
        const float nk = fmaxf(sqrtf(colsq[512 + h * 64 + d]), 1e-12f);
        float v = Sb[h * 4096 + d * 64 + t] / (nk * nq) * rsc;
        float m = v;
        #pragma unroll
        for (int off = 32; off > 0; off >>= 1) m = fmaxf(m, __shfl_xor(m, off, 64));
        float p = expf(v - m);
        float s = p;
        #pragma unroll
        for (int off = 32; off > 0; off >>= 1) s += __shfl_xor(s, off, 64);
        Abuf[h * 4096 + d * 64 + t] = p / s;
    }
}

// ---------------------------------------------------------------------------
// BtC[j][c]: c<512 -> fold attn with Wp; c>=512 -> W2. bsum[j] = bp[j]+b2[j].
// ---------------------------------------------------------------------------
__global__ void k_buildbt(const float* __restrict__ Abuf, const float* __restrict__ Wp,
                          const float* __restrict__ W2, const float* __restrict__ bp,
                          const float* __restrict__ b2, u16* __restrict__ BtC,
                          float* __restrict__ bsum)
{
    const int g = blockIdx.x * 256 + threadIdx.x;
    const int j = g >> 10, c = g & 1023;
    if (c < 512) {
        const int h = c >> 6, e = c & 63;
        const float* Ah = Abuf + h * 4096 + e;
        const float* Wph = Wp + (size_t)j * 512 + h * 64;
        float s = 0.f;
        #pragma unroll 8
        for (int d = 0; d < 64; ++d) s += Ah[d * 64] * Wph[d];
        BtC[(size_t)j * 1024 + c] = f2bf(s);
        if (c == 0) bsum[j] = bp[j] + b2[j];
    } else {
        BtC[(size_t)j * 1024 + c] = f2bf(W2[(size_t)j * 512 + (c - 512)]);
    }
}

// ---------------------------------------------------------------------------
extern "C" void kernel_launch(void* const* d_in, const int* in_sizes, int n_in,
                              void* d_out, int out_size, void* d_ws, size_t ws_size,
                              hipStream_t stream)
{
    const float* x_in    = (const float*)d_in[0];
    const float* task_x  = (const float*)d_in[1];
    const float* Ges     = (const float*)d_in[2];
    const float* Wq      = (const float*)d_in[3];
    const float* Wk      = (const float*)d_in[4];
    const float* Wv      = (const float*)d_in[5];
    const float* rescale = (const float*)d_in[6];
    const float* Wp      = (const float*)d_in[7];
    const float* bp      = (const float*)d_in[8];
    const float* W1      = (const float*)d_in[9];
    const float* b1      = (const float*)d_in[10];
    const float* W2      = (const float*)d_in[11];
    const float* b2      = (const float*)d_in[12];
    float* out = (float*)d_out;
    char* ws = (char*)d_ws;

    u16*   XB    = (u16*)  (ws + 0);            //  8192x512  bf16 (8 MB)
    u16*   TXT   = (u16*)  (ws + 8388608);      //  512x8192  bf16 (8 MB)
    u16*   QKV   = (u16*)  (ws + 16777216);     //  8192x1536 bf16 (25 MB)
    u16*   AH    = (u16*)  (ws + 41943040);     //  8192x1024 bf16 (17 MB)
    u16*   WqkvB = (u16*)  (ws + 58720256);     //  1536x512  bf16
    u16*   W1B   = (u16*)  (ws + 60293120);     //  512x512   bf16
    u16*   BtC   = (u16*)  (ws + 60817408);     //  512x1024  bf16
    float* colsq = (float*)(ws + 61865984);     //  1024 f32
    float* Sb    = (float*)(ws + 61870080);     //  8x64x64 f32
    float* Abuf  = (float*)(ws + 62001152);     //  8x64x64 f32
    float* bsum  = (float*)(ws + 62132224);     //  512 f32
    float* P     = (float*)(ws + 62134272);     //  4 x 8192x512 f32 (64 MB)
    u16*   GesB  = (u16*)  (ws + 129243136);    //  8192x8192 bf16 (134 MB)
    (void)in_sizes; (void)n_in; (void)out_size; (void)ws_size;  // ws >= 264 MB (observed ~1 GB)

    hipMemsetAsync(colsq, 0, 135168, stream);   // colsq + Sb

    k_convert  <<<2048, 256, 0, stream>>>(x_in, Wq, Wk, Wv, W1, XB, WqkvB, W1B);
    k_transpose<<<dim3(128, 8), 256, 0, stream>>>(task_x, TXT);
    k_cges     <<<2048, 256, 0, stream>>>(Ges, GesB);

    // QKV = x @ [Wq;Wk;Wv]^T  (M=8192, N=1536, K=512; 768 blocks, 3/CU)
    gemm_k<0><<<dim3(64, 12, 1), 256, 0, stream>>>(
        XB, 512, WqkvB, 512, QKV, 1536, 512);

    k_colsq  <<<128, 256, 0, stream>>>(QKV, colsq);
    k_gram   <<<512, 256, 0, stream>>>(QKV, Sb);
    k_softmax<<<8, 64, 0, stream>>>(Sb, colsq, rescale, Abuf);
    k_buildbt<<<2048, 256, 0, stream>>>(Abuf, Wp, W2, bp, b2, BtC, bsum);

    // guided partials: GesB @ TXT^T (M=8192, N=512, K=8192, split-K=4 -> 1024 blk, 4/CU)
    gemm_k<4><<<dim3(64, 4, 4), 256, 0, stream>>>(
        GesB, 8192, TXT, 8192, P, 512, 2048);
    k_cmb<4, 1><<<1024, 256, 0, stream>>>(P, QKV, nullptr, AH);

    // hidden partials: V @ W1^T  (K=512, split-K=2 -> 512 blk)
    gemm_k<4><<<dim3(64, 4, 2), 256, 0, stream>>>(
        QKV + 1024, 1536, W1B, 512, P, 512, 256);
    k_cmb<2, 2><<<1024, 256, 0, stream>>>(P, nullptr, b1, AH);

    // final partials: [guided|hidden] @ BtC^T  (K=1024, split-K=2 -> 512 blk)
    gemm_k<4><<<dim3(64, 4, 2), 256, 0, stream>>>(
        AH, 1024, BtC, 1024, P, 512, 512);
    k_cmb<2, 3><<<1024, 256, 0, stream>>>(P, nullptr, bsum, out);
}

// Round 10
// 407.008 us; speedup vs baseline: 1.0548x; 1.0248x over previous
//
#include <hip/hip_runtime.h>
#include <hip/hip_bf16.h>

typedef unsigned short u16;
typedef __attribute__((ext_vector_type(8))) short short8v;
typedef __attribute__((ext_vector_type(4))) float f32x4;

typedef __attribute__((address_space(3))) char lds_char;
typedef const __attribute__((address_space(1))) char g_char;

__device__ __forceinline__ u16 f2bf(float f) {
    union { float f; unsigned int u; } x; x.f = f;
    unsigned int u = x.u;
    return (u16)((u + 0x7FFFu + ((u >> 16) & 1u)) >> 16);
}
__device__ __forceinline__ float bf2f(u16 h) {
    union { unsigned int u; float f; } x; x.u = ((unsigned int)h) << 16;
    return x.f;
}
__device__ __forceinline__ u16 cvtbf(float f) {
    return __builtin_bit_cast(u16, __float2bfloat16(f));
}
__device__ __forceinline__ void gload16(const void* g, void* l) {
    __builtin_amdgcn_global_load_lds((g_char*)g, (lds_char*)l, 16, 0, 0);
}

// ---------------------------------------------------------------------------
// 256x128 bf16 MFMA GEMM, BK=64. 256 thr = 4 waves (2x2), wave tile 128x64
// (8x4 frags of 16x16x32) -> 64 MFMA per wave per K-step against 48KB staged:
// 2x the MFMA-per-staged-byte of the 128^2 tile (the r7-r9 pole). Single
// buffer LDS 48KB (A 32K | B 16K), all-DMA staging (pre-swizzled source),
// plain 2-barrier loop, 2 blocks/CU co-residency.
// Split-K: blockIdx.z handles K-chunk [z*K,(z+1)*K).
// EPI: 0 = store bf16, 4 = store f32 partial at P + z*8192*ldc.
// ---------------------------------------------------------------------------
template<int EPI>
__global__ __launch_bounds__(256, 2) void gemm_256(
    const u16* __restrict__ Ab, int lda,
    const u16* __restrict__ Bt, int ldb,
    void* __restrict__ Cp, int ldc, int K)
{
    __shared__ alignas(16) char smem[49152];   // A 32K | B 16K

    const int t     = threadIdx.x;
    const int lane  = t & 63;
    const int wid   = t >> 6;
    const int m0    = blockIdx.x * 256;
    const int n0    = blockIdx.y * 128;
    const int kbase = blockIdx.z * K;
    const int wr    = wid >> 1, wc = wid & 1;
    const int lr    = lane & 15, q4 = lane >> 4;

    f32x4 acc[8][4];
    #pragma unroll
    for (int i = 0; i < 8; ++i)
        #pragma unroll
        for (int j = 0; j < 4; ++j)
            acc[i][j] = (f32x4){0.f, 0.f, 0.f, 0.f};

    const int nsteps = K >> 6;
    for (int kt = 0; kt < nsteps; ++kt) {
        const int k0 = kbase + (kt << 6);
        // ---- stage A (256x64) + B (128x64), DMA, pre-swizzled source ----
        #pragma unroll
        for (int p = 0; p < 8; ++p) {
            int o   = p * 4096 + t * 16;
            int row = o >> 7;
            int cb  = (o & 127) ^ ((row & 7) << 4);
            gload16(Ab + (size_t)(m0 + row) * (size_t)lda + k0 + (cb >> 1),
                    smem + o);
        }
        #pragma unroll
        for (int p = 0; p < 4; ++p) {
            int o   = p * 4096 + t * 16;
            int row = o >> 7;
            int cb  = (o & 127) ^ ((row & 7) << 4);
            gload16(Bt + (size_t)(n0 + row) * (size_t)ldb + k0 + (cb >> 1),
                    smem + 32768 + o);
        }
        __syncthreads();   // vmcnt(0) drain + barrier: tile visible

        // ---- compute: 2 kh x (8x4) MFMA ----
        #pragma unroll
        for (int kh = 0; kh < 2; ++kh) {
            short8v a[8], b[4];
            #pragma unroll
            for (int i = 0; i < 8; ++i) {
                int ar = wr * 128 + i * 16 + lr;
                a[i] = *(const short8v*)(smem + ar * 128 +
                        ((kh * 64 + q4 * 16) ^ ((ar & 7) << 4)));
            }
            #pragma unroll
            for (int i = 0; i < 4; ++i) {
                int br = wc * 64 + i * 16 + lr;
                b[i] = *(const short8v*)(smem + 32768 + br * 128 +
                        ((kh * 64 + q4 * 16) ^ ((br & 7) << 4)));
            }
            #pragma unroll
            for (int mi = 0; mi < 8; ++mi)
                #pragma unroll
                for (int ni = 0; ni < 4; ++ni)
                    acc[mi][ni] = __builtin_amdgcn_mfma_f32_16x16x32_bf16(
                        a[mi], b[ni], acc[mi][ni], 0, 0, 0);
        }
        __syncthreads();   // all reads done before next stage overwrites
    }

    // ---- epilogue ----
    const size_t zoff = (size_t)blockIdx.z * 8192ull * (size_t)ldc;
    #pragma unroll
    for (int mi = 0; mi < 8; ++mi) {
        #pragma unroll
        for (int ni = 0; ni < 4; ++ni) {
            const int gc = n0 + wc * 64 + ni * 16 + lr;
            #pragma unroll
            for (int j = 0; j < 4; ++j) {
                const int gr = m0 + wr * 128 + mi * 16 + q4 * 4 + j;
                float v = acc[mi][ni][j];
                if constexpr (EPI == 0) {
                    ((u16*)Cp)[(size_t)gr * ldc + gc] = f2bf(v);
                } else {
                    ((float*)Cp)[zoff + (size_t)gr * ldc + gc] = v;
                }
            }
        }
    }
}

// ---------------------------------------------------------------------------
// m97-style 128x128 bf16 GEMM (kept for the small-K hidden/final GEMMs).
// ---------------------------------------------------------------------------
template<int EPI>
__global__ __launch_bounds__(256, 4) void gemm_k(
    const u16* __restrict__ Ab, int lda,
    const u16* __restrict__ Bt, int ldb,
    void* __restrict__ Cp, int ldc, int K)
{
    __shared__ alignas(16) char smem[32768];

    const int t     = threadIdx.x;
    const int lane  = t & 63;
    const int wid   = t >> 6;
    const int m0    = blockIdx.x * 128;
    const int n0    = blockIdx.y * 128;
    const int kbase = blockIdx.z * K;
    const int wr    = wid >> 1, wc = wid & 1;
    const int lr    = lane & 15, q4 = lane >> 4;

    f32x4 acc[4][4];
    #pragma unroll
    for (int i = 0; i < 4; ++i)
        #pragma unroll
        for (int j = 0; j < 4; ++j)
            acc[i][j] = (f32x4){0.f, 0.f, 0.f, 0.f};

    const int nsteps = K >> 6;
    for (int kt = 0; kt < nsteps; ++kt) {
        const int k0 = kbase + (kt << 6);
        #pragma unroll
        for (int p = 0; p < 4; ++p) {
            int o   = p * 4096 + t * 16;
            int row = o >> 7;
            int cb  = (o & 127) ^ ((row & 7) << 4);
            gload16(Ab + (size_t)(m0 + row) * (size_t)lda + k0 + (cb >> 1),
                    smem + o);
        }
        #pragma unroll
        for (int p = 0; p < 4; ++p) {
            int o   = p * 4096 + t * 16;
            int row = o >> 7;
            int cb  = (o & 127) ^ ((row & 7) << 4);
            gload16(Bt + (size_t)(n0 + row) * (size_t)ldb + k0 + (cb >> 1),
                    smem + 16384 + o);
        }
        __syncthreads();

        #pragma unroll
        for (int kh = 0; kh < 2; ++kh) {
            short8v a[4], b[4];
            #pragma unroll
            for (int i = 0; i < 4; ++i) {
                int ar = wr * 64 + i * 16 + lr;
                a[i] = *(const short8v*)(smem + ar * 128 +
                        ((kh * 64 + q4 * 16) ^ ((ar & 7) << 4)));
            }
            #pragma unroll
            for (int i = 0; i < 4; ++i) {
                int br = wc * 64 + i * 16 + lr;
                b[i] = *(const short8v*)(smem + 16384 + br * 128 +
                        ((kh * 64 + q4 * 16) ^ ((br & 7) << 4)));
            }
            #pragma unroll
            for (int mi = 0; mi < 4; ++mi)
                #pragma unroll
                for (int ni = 0; ni < 4; ++ni)
                    acc[mi][ni] = __builtin_amdgcn_mfma_f32_16x16x32_bf16(
                        a[mi], b[ni], acc[mi][ni], 0, 0, 0);
        }
        __syncthreads();
    }

    const size_t zoff = (size_t)blockIdx.z * 8192ull * (size_t)ldc;
    #pragma unroll
    for (int mi = 0; mi < 4; ++mi) {
        #pragma unroll
        for (int ni = 0; ni < 4; ++ni) {
            const int gc = n0 + wc * 64 + ni * 16 + lr;
            #pragma unroll
            for (int j = 0; j < 4; ++j) {
                const int gr = m0 + wr * 64 + mi * 16 + q4 * 4 + j;
                float v = acc[mi][ni][j];
                if constexpr (EPI == 0) {
                    ((u16*)Cp)[(size_t)gr * ldc + gc] = f2bf(v);
                } else {
                    ((float*)Cp)[zoff + (size_t)gr * ldc + gc] = v;
                }
            }
        }
    }
}

// ---------------------------------------------------------------------------
// Split-K combine + fused epilogues over [8192 x 512].
// MODE 1: AH[r][c]      = bf16( (sum_z P) * V[r][c] )        (guided * V)
// MODE 2: AH[r][512+c]  = bf16( gelu( sum_z P + b1[c] ) )    (MLP hidden)
// MODE 3: out[r][c]     = sum_z P + bsum[c]                   (final, f32)
// ---------------------------------------------------------------------------
template<int KZ, int MODE>
__global__ void k_cmb(const float* __restrict__ P, const u16* __restrict__ QKV,
                      const float* __restrict__ bvec, void* __restrict__ dst)
{
    for (int i = blockIdx.x * 256 + threadIdx.x; i < 1048576;
         i += gridDim.x * 256) {
        const int r = i >> 7, c = (i & 127) * 4;
        f32x4 s = ((const f32x4*)P)[i];
        #pragma unroll
        for (int z = 1; z < KZ; ++z) {
            f32x4 q = ((const f32x4*)P)[(size_t)z * 1048576 + i];
            s[0] += q[0]; s[1] += q[1]; s[2] += q[2]; s[3] += q[3];
        }
        if constexpr (MODE == 1) {
            ushort4 v = *(const ushort4*)(QKV + (size_t)r * 1536 + 1024 + c);
            ushort4 o;
            o.x = cvtbf(s[0] * bf2f(v.x)); o.y = cvtbf(s[1] * bf2f(v.y));
            o.z = cvtbf(s[2] * bf2f(v.z)); o.w = cvtbf(s[3] * bf2f(v.w));
            *(ushort4*)((u16*)dst + (size_t)r * 1024 + c) = o;
        } else if constexpr (MODE == 2) {
            float4 b = *(const float4*)(bvec + c);
            float x0 = s[0] + b.x, x1 = s[1] + b.y, x2 = s[2] + b.z, x3 = s[3] + b.w;
            ushort4 o;
            o.x = cvtbf(0.5f * x0 * (1.0f + erff(x0 * 0.70710678118f)));
            o.y = cvtbf(0.5f * x1 * (1.0f + erff(x1 * 0.70710678118f)));
            o.z = cvtbf(0.5f * x2 * (1.0f + erff(x2 * 0.70710678118f)));
            o.w = cvtbf(0.5f * x3 * (1.0f + erff(x3 * 0.70710678118f)));
            *(ushort4*)((u16*)dst + (size_t)r * 1024 + 512 + c) = o;
        } else {
            float4 b = *(const float4*)(bvec + c);
            float4 o = {s[0] + b.x, s[1] + b.y, s[2] + b.z, s[3] + b.w};
            *(float4*)((float*)dst + (size_t)r * 512 + c) = o;
        }
    }
}

// ---------------------------------------------------------------------------
// Ges fp32 -> bf16, streaming.
// ---------------------------------------------------------------------------
__global__ void k_cges(const float* __restrict__ g, u16* __restrict__ gb)
{
    const int total = 8388608;
    for (int i = blockIdx.x * 256 + threadIdx.x; i < total;
         i += gridDim.x * 256) {
        const float4* s = (const float4*)(g + (size_t)i * 8);
        float4 a = s[0], b = s[1];
        uint4 o;
        o.x = (unsigned)cvtbf(a.x) | ((unsigned)cvtbf(a.y) << 16);
        o.y = (unsigned)cvtbf(a.z) | ((unsigned)cvtbf(a.w) << 16);
        o.z = (unsigned)cvtbf(b.x) | ((unsigned)cvtbf(b.y) << 16);
        o.w = (unsigned)cvtbf(b.z) | ((unsigned)cvtbf(b.w) << 16);
        *(uint4*)(gb + (size_t)i * 8) = o;
    }
}

// ---------------------------------------------------------------------------
// Convert x_in, Wq|Wk|Wv (concat), W1 to bf16.
// ---------------------------------------------------------------------------
__global__ void k_convert(const float* __restrict__ x_in,
                          const float* __restrict__ Wq, const float* __restrict__ Wk,
                          const float* __restrict__ Wv, const float* __restrict__ W1,
                          u16* __restrict__ XB, u16* __restrict__ WqkvB,
                          u16* __restrict__ W1B)
{
    const int C1 = 1048576;
    const int C2 = 196608;
    const int C3 = 65536;
    for (int i = blockIdx.x * blockDim.x + threadIdx.x; i < C1 + C2 + C3;
         i += gridDim.x * blockDim.x) {
        const float* src; u16* dst;
        if (i < C1) { src = x_in + (size_t)i * 4; dst = XB + (size_t)i * 4; }
        else if (i < C1 + C2) {
            int e = (i - C1) * 4;
            if (e < 262144)      src = Wq + e;
            else if (e < 524288) src = Wk + (e - 262144);
            else                 src = Wv + (e - 524288);
            dst = WqkvB + e;
        } else {
            int e = (i - C1 - C2) * 4;
            src = W1 + e; dst = W1B + e;
        }
        float4 v = *reinterpret_cast<const float4*>(src);
        ushort4 h;
        h.x = f2bf(v.x); h.y = f2bf(v.y); h.z = f2bf(v.z); h.w = f2bf(v.w);
        *reinterpret_cast<ushort4*>(dst) = h;
    }
}

// ---------------------------------------------------------------------------
// TXT[c][m] = bf16(task_x[m][c])  — 64x64 tiles through LDS.
// ---------------------------------------------------------------------------
__global__ void k_transpose(const float* __restrict__ tx, u16* __restrict__ txt)
{
    __shared__ float tile[64][65];
    const int n0 = blockIdx.x * 64;
    const int c0 = blockIdx.y * 64;
    const int t = threadIdx.x;
    #pragma unroll
    for (int p = 0; p < 4; ++p) {
        int q = p * 256 + t;
        int r = q >> 4, s = q & 15;
        float4 v = *reinterpret_cast<const float4*>(tx + (size_t)(n0 + r) * 512 + c0 + s * 4);
        tile[r][s * 4 + 0] = v.x; tile[r][s * 4 + 1] = v.y;
        tile[r][s * 4 + 2] = v.z; tile[r][s * 4 + 3] = v.w;
    }
    __syncthreads();
    #pragma unroll
    for (int p = 0; p < 4; ++p) {
        int q = p * 256 + t;
        int cc = q >> 4, s = q & 15;
        ushort4 h;
        h.x = f2bf(tile[s * 4 + 0][cc]); h.y = f2bf(tile[s * 4 + 1][cc]);
        h.z = f2bf(tile[s * 4 + 2][cc]); h.w = f2bf(tile[s * 4 + 3][cc]);
        *reinterpret_cast<ushort4*>(txt + (size_t)(c0 + cc) * 8192 + n0 + s * 4) = h;
    }
}

// ---------------------------------------------------------------------------
// colsq[j] = sum_n QKV[n,j]^2, j in [0,1024)
// ---------------------------------------------------------------------------
__global__ void k_colsq(const u16* __restrict__ QKV, float* __restrict__ colsq)
{
    const int t = threadIdx.x;
    const int c8 = t & 127, rs = t >> 7;
    float a[8];
    #pragma unroll
    for (int j = 0; j < 8; ++j) a[j] = 0.f;
    const int row0 = blockIdx.x * 64;
    for (int rr = rs; rr < 64; rr += 2) {
        uint4 u = *reinterpret_cast<const uint4*>(QKV + (size_t)(row0 + rr) * 1536 + c8 * 8);
        unsigned int w[4] = {u.x, u.y, u.z, u.w};
        #pragma unroll
        for (int q = 0; q < 4; ++q) {
            float f0 = bf2f((u16)(w[q] & 0xffffu));
            float f1 = bf2f((u16)(w[q] >> 16));
            a[2 * q]     += f0 * f0;
            a[2 * q + 1] += f1 * f1;
        }
    }
    #pragma unroll
    for (int j = 0; j < 8; ++j) atomicAdd(&colsq[c8 * 8 + j], a[j]);
}

// ---------------------------------------------------------------------------
// Per-head Gram partials: S[h,d,e] += sum_{n in chunk} K[n,h64+d]*Q[n,h64+e]
// ---------------------------------------------------------------------------
__global__ void k_gram(const u16* __restrict__ QKV, float* __restrict__ Sb)
{
    __shared__ u16 Qt[4][64];
    __shared__ u16 Kt[4][64];
    const int h = blockIdx.x >> 6;
    const int chunk = blockIdx.x & 63;
    const int t = threadIdx.x;
    const int e = t & 63;
    const int dg = t >> 6;
    float acc[16];
    #pragma unroll
    for (int k = 0; k < 16; ++k) acc[k] = 0.f;
    const int rowbase = chunk * 128;
    for (int p = 0; p < 32; ++p) {
        __syncthreads();
        if (t < 64) {
            const int mat = t >> 5, sub = t & 31, r = sub >> 3, seg = sub & 7;
            const int row = rowbase + p * 4 + r;
            const int col = (mat ? 512 : 0) + h * 64 + seg * 8;
            uint4 v = *reinterpret_cast<const uint4*>(QKV + (size_t)row * 1536 + col);
            u16* dst = mat ? &Kt[r][seg * 8] : &Qt[r][seg * 8];
            *reinterpret_cast<uint4*>(dst) = v;
        }
        __syncthreads();
        #pragma unroll
        for (int r = 0; r < 4; ++r) {
            const float q = bf2f(Qt[r][e]);
            short8v kv0 = *reinterpret_cast<const short8v*>(&Kt[r][dg * 16]);
            short8v kv1 = *reinterpret_cast<const short8v*>(&Kt[r][dg * 16 + 8]);
            #pragma unroll
            for (int k = 0; k < 8; ++k) {
                acc[k]     += bf2f((u16)kv0[k]) * q;
                acc[k + 8] += bf2f((u16)kv1[k]) * q;
            }
        }
    }
    #pragma unroll
    for (int k = 0; k < 16; ++k)
        atomicAdd(&Sb[h * 4096 + (dg * 16 + k) * 64 + e], acc[k]);
}

// ---------------------------------------------------------------------------
// attn[h,d,e] = softmax_e( S/(||k_d|| ||q_e||) * rescale[h] )
// ---------------------------------------------------------------------------
__global__ void k_softmax(const float* __restrict__ Sb, const float* __restrict__ colsq,
                          const float* __restrict__ rescale, float* __restrict__ Abuf)
{
    const int h = blockIdx.x;
    const int t = threadIdx.x;   // 64
    const float rsc = rescale[h];
    const float nq = fmaxf(sqrtf(colsq[h * 64 + t]), 1e-12f);
    for (int d = 0; d < 64; ++d) {
        const float nk = fmaxf(sqrtf(colsq[512 + h * 64 + d]), 1e-12f);
        float v = Sb[h * 4096 + d * 64 + t] / (nk * nq) * rsc;
        float m = v;
        #pragma unroll
        for (int off = 32; off > 0; off >>= 1) m = fmaxf(m, __shfl_xor(m, off, 64));
        float p = expf(v - m);
        float s = p;
        #pragma unroll
        for (int off = 32; off > 0; off >>= 1) s += __shfl_xor(s, off, 64);
        Abuf[h * 4096 + d * 64 + t] = p / s;
    }
}

// ---------------------------------------------------------------------------
// BtC[j][c]: c<512 -> fold attn with Wp; c>=512 -> W2. bsum[j] = bp[j]+b2[j].
// ---------------------------------------------------------------------------
__global__ void k_buildbt(const float* __restrict__ Abuf, const float* __restrict__ Wp,
                          const float* __restrict__ W2, const float* __restrict__ bp,
                          const float* __restrict__ b2, u16* __restrict__ BtC,
                          float* __restrict__ bsum)
{
    const int g = blockIdx.x * 256 + threadIdx.x;
    const int j = g >> 10, c = g & 1023;
    if (c < 512) {
        const int h = c >> 6, e = c & 63;
        const float* Ah = Abuf + h * 4096 + e;
        const float* Wph = Wp + (size_t)j * 512 + h * 64;
        float s = 0.f;
        #pragma unroll 8
        for (int d = 0; d < 64; ++d) s += Ah[d * 64] * Wph[d];
        BtC[(size_t)j * 1024 + c] = f2bf(s);
        if (c == 0) bsum[j] = bp[j] + b2[j];
    } else {
        BtC[(size_t)j * 1024 + c] = f2bf(W2[(size_t)j * 512 + (c - 512)]);
    }
}

// ---------------------------------------------------------------------------
extern "C" void kernel_launch(void* const* d_in, const int* in_sizes, int n_in,
                              void* d_out, int out_size, void* d_ws, size_t ws_size,
                              hipStream_t stream)
{
    const float* x_in    = (const float*)d_in[0];
    const float* task_x  = (const float*)d_in[1];
    const float* Ges     = (const float*)d_in[2];
    const float* Wq      = (const float*)d_in[3];
    const float* Wk      = (const float*)d_in[4];
    const float* Wv      = (const float*)d_in[5];
    const float* rescale = (const float*)d_in[6];
    const float* Wp      = (const float*)d_in[7];
    const float* bp      = (const float*)d_in[8];
    const float* W1      = (const float*)d_in[9];
    const float* b1      = (const float*)d_in[10];
    const float* W2      = (const float*)d_in[11];
    const float* b2      = (const float*)d_in[12];
    float* out = (float*)d_out;
    char* ws = (char*)d_ws;

    u16*   XB    = (u16*)  (ws + 0);            //  8192x512  bf16 (8 MB)
    u16*   TXT   = (u16*)  (ws + 8388608);      //  512x8192  bf16 (8 MB)
    u16*   QKV   = (u16*)  (ws + 16777216);     //  8192x1536 bf16 (25 MB)
    u16*   AH    = (u16*)  (ws + 41943040);     //  8192x1024 bf16 (17 MB)
    u16*   WqkvB = (u16*)  (ws + 58720256);     //  1536x512  bf16
    u16*   W1B   = (u16*)  (ws + 60293120);     //  512x512   bf16
    u16*   BtC   = (u16*)  (ws + 60817408);     //  512x1024  bf16
    float* colsq = (float*)(ws + 61865984);     //  1024 f32
    float* Sb    = (float*)(ws + 61870080);     //  8x64x64 f32
    float* Abuf  = (float*)(ws + 62001152);     //  8x64x64 f32
    float* bsum  = (float*)(ws + 62132224);     //  512 f32
    float* P     = (float*)(ws + 62134272);     //  4 x 8192x512 f32 (64 MB)
    u16*   GesB  = (u16*)  (ws + 129243136);    //  8192x8192 bf16 (134 MB)
    (void)in_sizes; (void)n_in; (void)out_size; (void)ws_size;

    hipMemsetAsync(colsq, 0, 135168, stream);   // colsq + Sb

    k_convert  <<<2048, 256, 0, stream>>>(x_in, Wq, Wk, Wv, W1, XB, WqkvB, W1B);
    k_transpose<<<dim3(128, 8), 256, 0, stream>>>(task_x, TXT);
    k_cges     <<<2048, 256, 0, stream>>>(Ges, GesB);

    // QKV = x @ [Wq;Wk;Wv]^T  (M=8192, N=1536, K=512; 256-tile, 384 blocks)
    gemm_256<0><<<dim3(32, 12, 1), 256, 0, stream>>>(
        XB, 512, WqkvB, 512, QKV, 1536, 512);

    k_colsq  <<<128, 256, 0, stream>>>(QKV, colsq);
    k_gram   <<<512, 256, 0, stream>>>(QKV, Sb);
    k_softmax<<<8, 64, 0, stream>>>(Sb, colsq, rescale, Abuf);
    k_buildbt<<<2048, 256, 0, stream>>>(Abuf, Wp, W2, bp, b2, BtC, bsum);

    // guided partials: GesB @ TXT^T (M=8192, N=512, K=8192; 256-tile,
    // split-K=4 -> (32,4,4) = 512 blocks = 2/CU exactly)
    gemm_256<4><<<dim3(32, 4, 4), 256, 0, stream>>>(
        GesB, 8192, TXT, 8192, P, 512, 2048);
    k_cmb<4, 1><<<1024, 256, 0, stream>>>(P, QKV, nullptr, AH);

    // hidden partials: V @ W1^T  (K=512, split-K=2 -> 512 blk, 128^2 tile)
    gemm_k<4><<<dim3(64, 4, 2), 256, 0, stream>>>(
        QKV + 1024, 1536, W1B, 512, P, 512, 256);
    k_cmb<2, 2><<<1024, 256, 0, stream>>>(P, nullptr, b1, AH);

    // final partials: [guided|hidden] @ BtC^T  (K=1024, split-K=2 -> 512 blk)
    gemm_k<4><<<dim3(64, 4, 2), 256, 0, stream>>>(
        AH, 1024, BtC, 1024, P, 512, 512);
    k_cmb<2, 3><<<1024, 256, 0, stream>>>(P, nullptr, bsum, out);
}